// Round 1
// baseline (5342.400 us; speedup 1.0000x reference)
//
#include <hip/hip_runtime.h>
#include <math.h>

#define NR 5
#define NB 7
#define NS 119
#define NA 25000
#define NE 1000000
#define OC 360           // output columns per atom
#define MUS 100          // unique moment floats per atom

// tril index tables (runtime-indexed)
static constexpr int T2I[15] = {0,1,1,2,2,2,3,3,3,3,4,4,4,4,4};
static constexpr int T2J[15] = {0,0,1,0,1,2,0,1,2,3,0,1,2,3,4};
static constexpr int T3I[35] = {0,1,1,1,2,2,2,2,2,2,3,3,3,3,3,3,3,3,3,3,4,4,4,4,4,4,4,4,4,4,4,4,4,4,4};
static constexpr int T3J[35] = {0,0,1,1,0,1,1,2,2,2,0,1,1,2,2,2,3,3,3,3,0,1,1,2,2,2,3,3,3,3,4,4,4,4,4};
static constexpr int T3K[35] = {0,0,0,1,0,0,1,0,1,2,0,0,1,0,1,2,0,1,2,3,0,0,1,0,1,2,0,1,2,3,0,1,2,3,4};

// symmetric-storage index maps (compile-time folded inside unrolled loops)
// unique pair order: (00),(10),(20),(11),(21),(22)
static constexpr int P2[9]  = {0,1,2, 1,3,4, 2,4,5};
// unique triple order: (000),(100),(110),(111),(200),(210),(211),(220),(221),(222)
static constexpr int P3[27] = {0,1,4, 1,2,5, 4,5,7,
                               1,2,5, 2,3,6, 5,6,8,
                               4,5,7, 5,6,8, 7,8,9};
static constexpr float W2[6]  = {1.f,2.f,2.f,1.f,2.f,1.f};
static constexpr float W3[10] = {1.f,3.f,3.f,1.f,3.f,6.f,3.f,3.f,3.f,1.f};

__device__ __forceinline__ void atomic_add_f32(float* p, float v) {
    __hip_atomic_fetch_add(p, v, __ATOMIC_RELAXED, __HIP_MEMORY_SCOPE_AGENT);
}

// ---------------- edge kernel: accumulate unique moments per atom --------
__global__ __launch_bounds__(256) void edge_kernel(
    const float* __restrict__ dr_vec, const int* __restrict__ Z,
    const int* __restrict__ nbr, const float* __restrict__ coeffs,
    float* __restrict__ Mu)
{
    int e = blockIdx.x * 256 + threadIdx.x;
    if (e >= NE) return;
    float x = dr_vec[3*e+0], y = dr_vec[3*e+1], z = dr_vec[3*e+2];
    int ai = nbr[e];        // idx_i
    int aj = nbr[NE + e];   // idx_j  (segment target)
    int Zi = Z[ai], Zj = Z[aj];

    float dr  = sqrtf(x*x + y*y + z*z);
    float inv = 1.0f / (dr + 1e-5f);
    float d0 = x*inv, d1 = y*inv, d2 = z*inv;

    const float betta = 49.0f / 36.0f;       // NB^2 / R_MAX^2
    const float PI_F  = 3.14159265358979323846f;
    float rad_norm = powf(2.0f*betta/PI_F, 0.75f);
    float cut = (dr < 6.0f) ? 0.5f*(cosf(PI_F * dr * (1.0f/6.0f)) + 1.0f) : 0.0f;
    float scale = cut * 0.3779644730092272272f;   // 1/sqrt(7)

    float basis[NB];
#pragma unroll
    for (int b = 0; b < NB; b++) {
        float t = dr - (float)b;              // shifts = 0,1,2,3,4,5,6
        basis[b] = rad_norm * expf(-betta * t * t);
    }

    const float* cp = coeffs + ((size_t)(Zi*NS + Zj)) * (NR*NB);
    float rad[NR];
#pragma unroll
    for (int r = 0; r < NR; r++) {
        float s = 0.f;
#pragma unroll
        for (int b = 0; b < NB; b++) s += basis[b] * cp[r*NB + b];
        rad[r] = s * scale;
    }

    // unique geometric products
    float q2[6] = {d0*d0, d1*d0, d2*d0, d1*d1, d2*d1, d2*d2};
    float q3[10] = {d0*q2[0], d1*q2[0], d0*q2[3], d1*q2[3], d2*q2[0],
                    d2*q2[1], d2*q2[3], d0*q2[5], d1*q2[5], d2*q2[5]};

    float* M = Mu + (size_t)aj * MUS;
#pragma unroll
    for (int r = 0; r < NR; r++) {
        float rv = rad[r];
        atomic_add_f32(&M[r], rv);
        atomic_add_f32(&M[5 + r*3 + 0], rv*d0);
        atomic_add_f32(&M[5 + r*3 + 1], rv*d1);
        atomic_add_f32(&M[5 + r*3 + 2], rv*d2);
#pragma unroll
        for (int p = 0; p < 6; p++)  atomic_add_f32(&M[20 + r*6  + p], rv*q2[p]);
#pragma unroll
        for (int p = 0; p < 10; p++) atomic_add_f32(&M[50 + r*10 + p], rv*q3[p]);
    }
}

// ---------------- accessors over unique moment storage -------------------
__device__ __forceinline__ float m1v(const float* M, int r, int i) {
    return M[5 + r*3 + i];
}

// ---------------- contraction kernel: one thread per output element ------
// Reference reshapes are raw C-order reshapes of pair-major (W, A) buffers:
// out[a*360 + off + k] = C[l][a2] with f = a*W + k, l = f/NA, a2 = f%NA.
__global__ __launch_bounds__(256) void contract_kernel(
    const float* __restrict__ Mu, float* __restrict__ out)
{
    int o = blockIdx.x * 256 + threadIdx.x;
    if (o >= NA * OC) return;
    int a = o / OC;
    int c = o - a * OC;
    float v;

    if (c < 5) {
        // contr_0 = m0, atom-major, no scramble
        v = Mu[(size_t)a * MUS + c];
    } else if (c < 20) {
        // contr_1: sum_i m1[r,i] m1[s,i], W=15
        int f = a*15 + (c - 5); int l = f / NA; int a2 = f - l*NA;
        const float* M = Mu + (size_t)a2 * MUS;
        int r = T2I[l], s = T2J[l];
        float acc = 0.f;
#pragma unroll
        for (int i = 0; i < 3; i++) acc += m1v(M,r,i) * m1v(M,s,i);
        v = acc;
    } else if (c < 35) {
        // contr_2: sum_ij m2 m2 (weighted unique), W=15
        int f = a*15 + (c - 20); int l = f / NA; int a2 = f - l*NA;
        const float* M = Mu + (size_t)a2 * MUS;
        int r = T2I[l], s = T2J[l];
        float acc = 0.f;
#pragma unroll
        for (int p = 0; p < 6; p++) acc += W2[p] * M[20 + r*6 + p] * M[20 + s*6 + p];
        v = acc;
    } else if (c < 50) {
        // contr_3: sum_ijk m3 m3 (weighted unique), W=15
        int f = a*15 + (c - 35); int l = f / NA; int a2 = f - l*NA;
        const float* M = Mu + (size_t)a2 * MUS;
        int r = T2I[l], s = T2J[l];
        float acc = 0.f;
#pragma unroll
        for (int p = 0; p < 10; p++) acc += W3[p] * M[50 + r*10 + p] * M[50 + s*10 + p];
        v = acc;
    } else if (c < 85) {
        // contr_4: sum_ijk m2[r,ij] m2[s,ik] m2[t,jk], W=35 (tril3)
        int f = a*35 + (c - 50); int l = f / NA; int a2 = f - l*NA;
        const float* M = Mu + (size_t)a2 * MUS;
        int r = T3I[l], s = T3J[l], t = T3K[l];
        float R[6], S[6], T[6];
#pragma unroll
        for (int p = 0; p < 6; p++) { R[p]=M[20+r*6+p]; S[p]=M[20+s*6+p]; T[p]=M[20+t*6+p]; }
        float acc = 0.f;
#pragma unroll
        for (int i = 0; i < 3; i++)
#pragma unroll
        for (int j = 0; j < 3; j++)
#pragma unroll
        for (int k = 0; k < 3; k++)
            acc += R[P2[i*3+j]] * S[P2[i*3+k]] * T[P2[j*3+k]];
        v = acc;
    } else if (c < 160) {
        // contr_5: sum_ij m1[r,i] m1[s,j] m2[t,ij], W=75, l = pair*5 + t
        int f = a*75 + (c - 85); int l = f / NA; int a2 = f - l*NA;
        const float* M = Mu + (size_t)a2 * MUS;
        int p = l / 5, t = l - p*5;
        int r = T2I[p], s = T2J[p];
        float T[6];
#pragma unroll
        for (int q = 0; q < 6; q++) T[q] = M[20 + t*6 + q];
        float acc = 0.f;
#pragma unroll
        for (int i = 0; i < 3; i++)
#pragma unroll
        for (int j = 0; j < 3; j++)
            acc += m1v(M,r,i) * m1v(M,s,j) * T[P2[i*3+j]];
        v = acc;
    } else if (c < 235) {
        // contr_6: sum_ijkl m3[r,ijk] m3[s,ijl] m2[t,kl], W=75
        int f = a*75 + (c - 160); int l = f / NA; int a2 = f - l*NA;
        const float* M = Mu + (size_t)a2 * MUS;
        int p = l / 5, t = l - p*5;
        int r = T2I[p], s = T2J[p];
        float R[10], S[10], T[6];
#pragma unroll
        for (int q = 0; q < 10; q++) { R[q]=M[50+r*10+q]; S[q]=M[50+s*10+q]; }
#pragma unroll
        for (int q = 0; q < 6;  q++) T[q] = M[20 + t*6 + q];
        float acc = 0.f;
#pragma unroll
        for (int k = 0; k < 3; k++)
#pragma unroll
        for (int l2 = 0; l2 < 3; l2++) {
            float inner = 0.f;
#pragma unroll
            for (int i = 0; i < 3; i++)
#pragma unroll
            for (int j = 0; j < 3; j++)
                inner += R[P3[(i*3+j)*3+k]] * S[P3[(i*3+j)*3+l2]];
            acc += inner * T[P2[k*3+l2]];
        }
        v = acc;
    } else {
        // contr_7: sum_ijk m3[r,ijk] m2[s,ij] m1[t,k], W=125, l = r*25+s*5+t
        int f = a*125 + (c - 235); int l = f / NA; int a2 = f - l*NA;
        const float* M = Mu + (size_t)a2 * MUS;
        int r = l / 25; int rem = l - r*25; int s = rem / 5; int t = rem - s*5;
        float R[10], S[6], T1[3];
#pragma unroll
        for (int q = 0; q < 10; q++) R[q] = M[50 + r*10 + q];
#pragma unroll
        for (int q = 0; q < 6;  q++) S[q] = M[20 + s*6 + q];
#pragma unroll
        for (int q = 0; q < 3;  q++) T1[q] = M[5 + t*3 + q];
        float acc = 0.f;
#pragma unroll
        for (int i = 0; i < 3; i++)
#pragma unroll
        for (int j = 0; j < 3; j++)
#pragma unroll
        for (int k = 0; k < 3; k++)
            acc += R[P3[(i*3+j)*3+k]] * S[P2[i*3+j]] * T1[k];
        v = acc;
    }
    out[o] = v;
}

extern "C" void kernel_launch(void* const* d_in, const int* in_sizes, int n_in,
                              void* d_out, int out_size, void* d_ws, size_t ws_size,
                              hipStream_t stream) {
    const float* dr_vec = (const float*)d_in[0];
    const int*   Z      = (const int*)d_in[1];
    const int*   nbr    = (const int*)d_in[2];
    const float* coeffs = (const float*)d_in[3];
    float* out = (float*)d_out;
    float* Mu  = (float*)d_ws;   // NA * 100 floats = 10 MB

    hipMemsetAsync(Mu, 0, (size_t)NA * MUS * sizeof(float), stream);
    edge_kernel<<<(NE + 255)/256, 256, 0, stream>>>(dr_vec, Z, nbr, coeffs, Mu);
    contract_kernel<<<((NA*OC) + 255)/256, 256, 0, stream>>>(Mu, out);
}

// Round 2
// 482.708 us; speedup vs baseline: 11.0676x; 11.0676x over previous
//
#include <hip/hip_runtime.h>
#include <math.h>

#define NR 5
#define NB 7
#define NS 119
#define NA 25000
#define NE 1000000
#define OC 360           // output columns per atom
#define MUS 100          // unique moment floats per atom
#define CAP 112          // max edges binned per atom (lambda=40, P(overflow)~1e-19)

// tril index tables (runtime-indexed)
static constexpr int T2I[15] = {0,1,1,2,2,2,3,3,3,3,4,4,4,4,4};
static constexpr int T2J[15] = {0,0,1,0,1,2,0,1,2,3,0,1,2,3,4};
static constexpr int T3I[35] = {0,1,1,1,2,2,2,2,2,2,3,3,3,3,3,3,3,3,3,3,4,4,4,4,4,4,4,4,4,4,4,4,4,4,4};
static constexpr int T3J[35] = {0,0,1,1,0,1,1,2,2,2,0,1,1,2,2,2,3,3,3,3,0,1,1,2,2,2,3,3,3,3,4,4,4,4,4};
static constexpr int T3K[35] = {0,0,0,1,0,0,1,0,1,2,0,0,1,0,1,2,0,1,2,3,0,0,1,0,1,2,0,1,2,3,0,1,2,3,4};

// symmetric-storage index maps
// unique pair order: (00),(10),(20),(11),(21),(22)
static constexpr int P2[9]  = {0,1,2, 1,3,4, 2,4,5};
// unique triple order: (000),(100),(110),(111),(200),(210),(211),(220),(221),(222)
static constexpr int P3[27] = {0,1,4, 1,2,5, 4,5,7,
                               1,2,5, 2,3,6, 5,6,8,
                               4,5,7, 5,6,8, 7,8,9};
static constexpr float W2[6]  = {1.f,2.f,2.f,1.f,2.f,1.f};
static constexpr float W3[10] = {1.f,3.f,3.f,1.f,3.f,6.f,3.f,3.f,3.f,1.f};

// ---------------- pass 1: bin edge ids by target atom --------------------
__global__ __launch_bounds__(256) void scatter_kernel(
    const int* __restrict__ nbr, int* __restrict__ cursor, int* __restrict__ bins)
{
    int e = blockIdx.x * 256 + threadIdx.x;
    if (e >= NE) return;
    int aj = nbr[NE + e];
    int pos = __hip_atomic_fetch_add(&cursor[aj], 1, __ATOMIC_RELAXED, __HIP_MEMORY_SCOPE_AGENT);
    if (pos < CAP) bins[(size_t)aj * CAP + pos] = e;
}

// ---------------- pass 2: one thread per atom, accumulate moments --------
__global__ __launch_bounds__(64) void accum_kernel(
    const float* __restrict__ dr_vec, const int* __restrict__ Z,
    const int* __restrict__ nbr, const float* __restrict__ coeffs,
    const int* __restrict__ cursor, const int* __restrict__ bins,
    float* __restrict__ Mu)
{
    int a = blockIdx.x * 64 + threadIdx.x;
    if (a >= NA) return;
    int n = cursor[a]; if (n > CAP) n = CAP;
    int Zj = Z[a];

    float acc[MUS];
#pragma unroll
    for (int i = 0; i < MUS; i++) acc[i] = 0.f;

    const int* mybin = bins + (size_t)a * CAP;
    const float PI_F = 3.14159265358979323846f;
    const float betta = 49.0f / 36.0f;
    float rad_norm = powf(2.0f * betta / PI_F, 0.75f);

    for (int p = 0; p < n; p++) {
        int e = mybin[p];
        float x = dr_vec[3*e+0], y = dr_vec[3*e+1], z = dr_vec[3*e+2];
        int Zi = Z[nbr[e]];

        float dr  = sqrtf(x*x + y*y + z*z);
        float inv = 1.0f / (dr + 1e-5f);
        float d0 = x*inv, d1 = y*inv, d2 = z*inv;

        float cut = (dr < 6.0f) ? 0.5f*(cosf(PI_F * dr * (1.0f/6.0f)) + 1.0f) : 0.0f;
        float scale = cut * 0.3779644730092272272f;   // 1/sqrt(7)

        float basis[NB];
#pragma unroll
        for (int b = 0; b < NB; b++) {
            float t = dr - (float)b;
            basis[b] = rad_norm * expf(-betta * t * t);
        }

        const float* cp = coeffs + ((size_t)(Zi*NS + Zj)) * (NR*NB);
        float rad[NR];
#pragma unroll
        for (int r = 0; r < NR; r++) {
            float s = 0.f;
#pragma unroll
            for (int b = 0; b < NB; b++) s += basis[b] * cp[r*NB + b];
            rad[r] = s * scale;
        }

        float q2[6] = {d0*d0, d1*d0, d2*d0, d1*d1, d2*d1, d2*d2};
        float q3[10] = {d0*q2[0], d1*q2[0], d0*q2[3], d1*q2[3], d2*q2[0],
                        d2*q2[1], d2*q2[3], d0*q2[5], d1*q2[5], d2*q2[5]};

#pragma unroll
        for (int r = 0; r < NR; r++) {
            float rv = rad[r];
            acc[r] += rv;
            acc[5 + r*3 + 0] += rv*d0;
            acc[5 + r*3 + 1] += rv*d1;
            acc[5 + r*3 + 2] += rv*d2;
#pragma unroll
            for (int q = 0; q < 6; q++)  acc[20 + r*6  + q] += rv*q2[q];
#pragma unroll
            for (int q = 0; q < 10; q++) acc[50 + r*10 + q] += rv*q3[q];
        }
    }

    float* M = Mu + (size_t)a * MUS;
#pragma unroll
    for (int i = 0; i < MUS; i++) M[i] = acc[i];
}

// ---------------- accessors over unique moment storage -------------------
__device__ __forceinline__ float m1v(const float* M, int r, int i) {
    return M[5 + r*3 + i];
}

// ---------------- contraction kernel: one thread per output element ------
__global__ __launch_bounds__(256) void contract_kernel(
    const float* __restrict__ Mu, float* __restrict__ out)
{
    int o = blockIdx.x * 256 + threadIdx.x;
    if (o >= NA * OC) return;
    int a = o / OC;
    int c = o - a * OC;
    float v;

    if (c < 5) {
        v = Mu[(size_t)a * MUS + c];
    } else if (c < 20) {
        int f = a*15 + (c - 5); int l = f / NA; int a2 = f - l*NA;
        const float* M = Mu + (size_t)a2 * MUS;
        int r = T2I[l], s = T2J[l];
        float acc = 0.f;
#pragma unroll
        for (int i = 0; i < 3; i++) acc += m1v(M,r,i) * m1v(M,s,i);
        v = acc;
    } else if (c < 35) {
        int f = a*15 + (c - 20); int l = f / NA; int a2 = f - l*NA;
        const float* M = Mu + (size_t)a2 * MUS;
        int r = T2I[l], s = T2J[l];
        float acc = 0.f;
#pragma unroll
        for (int p = 0; p < 6; p++) acc += W2[p] * M[20 + r*6 + p] * M[20 + s*6 + p];
        v = acc;
    } else if (c < 50) {
        int f = a*15 + (c - 35); int l = f / NA; int a2 = f - l*NA;
        const float* M = Mu + (size_t)a2 * MUS;
        int r = T2I[l], s = T2J[l];
        float acc = 0.f;
#pragma unroll
        for (int p = 0; p < 10; p++) acc += W3[p] * M[50 + r*10 + p] * M[50 + s*10 + p];
        v = acc;
    } else if (c < 85) {
        int f = a*35 + (c - 50); int l = f / NA; int a2 = f - l*NA;
        const float* M = Mu + (size_t)a2 * MUS;
        int r = T3I[l], s = T3J[l], t = T3K[l];
        float R[6], S[6], T[6];
#pragma unroll
        for (int p = 0; p < 6; p++) { R[p]=M[20+r*6+p]; S[p]=M[20+s*6+p]; T[p]=M[20+t*6+p]; }
        float acc = 0.f;
#pragma unroll
        for (int i = 0; i < 3; i++)
#pragma unroll
        for (int j = 0; j < 3; j++)
#pragma unroll
        for (int k = 0; k < 3; k++)
            acc += R[P2[i*3+j]] * S[P2[i*3+k]] * T[P2[j*3+k]];
        v = acc;
    } else if (c < 160) {
        int f = a*75 + (c - 85); int l = f / NA; int a2 = f - l*NA;
        const float* M = Mu + (size_t)a2 * MUS;
        int p = l / 5, t = l - p*5;
        int r = T2I[p], s = T2J[p];
        float T[6];
#pragma unroll
        for (int q = 0; q < 6; q++) T[q] = M[20 + t*6 + q];
        float acc = 0.f;
#pragma unroll
        for (int i = 0; i < 3; i++)
#pragma unroll
        for (int j = 0; j < 3; j++)
            acc += m1v(M,r,i) * m1v(M,s,j) * T[P2[i*3+j]];
        v = acc;
    } else if (c < 235) {
        int f = a*75 + (c - 160); int l = f / NA; int a2 = f - l*NA;
        const float* M = Mu + (size_t)a2 * MUS;
        int p = l / 5, t = l - p*5;
        int r = T2I[p], s = T2J[p];
        float R[10], S[10], T[6];
#pragma unroll
        for (int q = 0; q < 10; q++) { R[q]=M[50+r*10+q]; S[q]=M[50+s*10+q]; }
#pragma unroll
        for (int q = 0; q < 6;  q++) T[q] = M[20 + t*6 + q];
        float acc = 0.f;
#pragma unroll
        for (int k = 0; k < 3; k++)
#pragma unroll
        for (int l2 = 0; l2 < 3; l2++) {
            float inner = 0.f;
#pragma unroll
            for (int i = 0; i < 3; i++)
#pragma unroll
            for (int j = 0; j < 3; j++)
                inner += R[P3[(i*3+j)*3+k]] * S[P3[(i*3+j)*3+l2]];
            acc += inner * T[P2[k*3+l2]];
        }
        v = acc;
    } else {
        int f = a*125 + (c - 235); int l = f / NA; int a2 = f - l*NA;
        const float* M = Mu + (size_t)a2 * MUS;
        int r = l / 25; int rem = l - r*25; int s = rem / 5; int t = rem - s*5;
        float R[10], S[6], T1[3];
#pragma unroll
        for (int q = 0; q < 10; q++) R[q] = M[50 + r*10 + q];
#pragma unroll
        for (int q = 0; q < 6;  q++) S[q] = M[20 + s*6 + q];
#pragma unroll
        for (int q = 0; q < 3;  q++) T1[q] = M[5 + t*3 + q];
        float acc = 0.f;
#pragma unroll
        for (int i = 0; i < 3; i++)
#pragma unroll
        for (int j = 0; j < 3; j++)
#pragma unroll
        for (int k = 0; k < 3; k++)
            acc += R[P3[(i*3+j)*3+k]] * S[P2[i*3+j]] * T1[k];
        v = acc;
    }
    out[o] = v;
}

extern "C" void kernel_launch(void* const* d_in, const int* in_sizes, int n_in,
                              void* d_out, int out_size, void* d_ws, size_t ws_size,
                              hipStream_t stream) {
    const float* dr_vec = (const float*)d_in[0];
    const int*   Z      = (const int*)d_in[1];
    const int*   nbr    = (const int*)d_in[2];
    const float* coeffs = (const float*)d_in[3];
    float* out = (float*)d_out;

    // workspace layout: cursor[NA] | bins[NA*CAP] | Mu[NA*MUS]  (~21.3 MB)
    int*   cursor = (int*)d_ws;
    int*   bins   = cursor + NA;
    float* Mu     = (float*)(bins + (size_t)NA * CAP);

    hipMemsetAsync(cursor, 0, (size_t)NA * sizeof(int), stream);
    scatter_kernel<<<(NE + 255)/256, 256, 0, stream>>>(nbr, cursor, bins);
    accum_kernel<<<(NA + 63)/64, 64, 0, stream>>>(dr_vec, Z, nbr, coeffs, cursor, bins, Mu);
    contract_kernel<<<((NA*OC) + 255)/256, 256, 0, stream>>>(Mu, out);
}

// Round 3
// 285.858 us; speedup vs baseline: 18.6890x; 1.6886x over previous
//
#include <hip/hip_runtime.h>
#include <math.h>

#define NR 5
#define NB 7
#define NS 119
#define NA 25000
#define NE 1000000
#define OC 360           // output columns per atom
#define MUS 100          // unique moment floats per atom
#define CAP 112          // max edges binned per atom (lambda=40, P(overflow)~1e-19)
#define CHUNK 64         // atoms per contract block
#define MPAD 101         // LDS stride: 101 mod 32 = 5, gcd(5,32)=1 -> conflict-free

// tril index tables (runtime-indexed, wave-uniform index -> scalar loads)
static constexpr int T2I[15] = {0,1,1,2,2,2,3,3,3,3,4,4,4,4,4};
static constexpr int T2J[15] = {0,0,1,0,1,2,0,1,2,3,0,1,2,3,4};
static constexpr int T3I[35] = {0,1,1,1,2,2,2,2,2,2,3,3,3,3,3,3,3,3,3,3,4,4,4,4,4,4,4,4,4,4,4,4,4,4,4};
static constexpr int T3J[35] = {0,0,1,1,0,1,1,2,2,2,0,1,1,2,2,2,3,3,3,3,0,1,1,2,2,2,3,3,3,3,4,4,4,4,4};
static constexpr int T3K[35] = {0,0,0,1,0,0,1,0,1,2,0,0,1,0,1,2,0,1,2,3,0,0,1,0,1,2,0,1,2,3,0,1,2,3,4};

// symmetric-storage index maps (compile-time folded in unrolled loops)
static constexpr int P2[9]  = {0,1,2, 1,3,4, 2,4,5};
static constexpr int P3[27] = {0,1,4, 1,2,5, 4,5,7,
                               1,2,5, 2,3,6, 5,6,8,
                               4,5,7, 5,6,8, 7,8,9};
static constexpr float W2[6]  = {1.f,2.f,2.f,1.f,2.f,1.f};
static constexpr float W3[10] = {1.f,3.f,3.f,1.f,3.f,6.f,3.f,3.f,3.f,1.f};

// ---------------- pass 1: bin edge ids by target atom --------------------
__global__ __launch_bounds__(256) void scatter_kernel(
    const int* __restrict__ nbr, int* __restrict__ cursor, int* __restrict__ bins)
{
    int e = blockIdx.x * 256 + threadIdx.x;
    if (e >= NE) return;
    int aj = nbr[NE + e];
    int pos = __hip_atomic_fetch_add(&cursor[aj], 1, __ATOMIC_RELAXED, __HIP_MEMORY_SCOPE_AGENT);
    if (pos < CAP) bins[(size_t)aj * CAP + pos] = e;
}

// ---------------- pass 2: 8 threads per atom, shuffle-reduce -------------
__global__ __launch_bounds__(256) void accum_kernel(
    const float* __restrict__ dr_vec, const int* __restrict__ Z,
    const int* __restrict__ nbr, const float* __restrict__ coeffs,
    const int* __restrict__ cursor, const int* __restrict__ bins,
    float* __restrict__ Mu)
{
    __shared__ float red[32 * MUS];               // 32 atoms/block
    int t   = blockIdx.x * 256 + threadIdx.x;
    int a   = t >> 3;                             // global atom
    int sub = t & 7;
    int al  = threadIdx.x >> 3;                   // local atom 0..31
    int n   = (a < NA) ? min(cursor[a], CAP) : 0;
    int Zj  = (a < NA) ? Z[a] : 0;

    float acc[MUS];
#pragma unroll
    for (int i = 0; i < MUS; i++) acc[i] = 0.f;

    const int* mybin = bins + (size_t)a * CAP;
    const float PI_F = 3.14159265358979323846f;
    const float betta = 49.0f / 36.0f;
    float rad_norm = powf(2.0f * betta / PI_F, 0.75f);

    for (int p = sub; p < n; p += 8) {
        int e = mybin[p];
        float x = dr_vec[3*e+0], y = dr_vec[3*e+1], z = dr_vec[3*e+2];
        int Zi = Z[nbr[e]];

        float dr  = sqrtf(x*x + y*y + z*z);
        float inv = 1.0f / (dr + 1e-5f);
        float d0 = x*inv, d1 = y*inv, d2 = z*inv;

        float cut = (dr < 6.0f) ? 0.5f*(cosf(PI_F * dr * (1.0f/6.0f)) + 1.0f) : 0.0f;
        float scale = cut * 0.3779644730092272272f;   // 1/sqrt(7)

        float basis[NB];
#pragma unroll
        for (int b = 0; b < NB; b++) {
            float tt = dr - (float)b;
            basis[b] = rad_norm * expf(-betta * tt * tt);
        }

        const float* cp = coeffs + ((size_t)(Zi*NS + Zj)) * (NR*NB);
        float rad[NR];
#pragma unroll
        for (int r = 0; r < NR; r++) {
            float s = 0.f;
#pragma unroll
            for (int b = 0; b < NB; b++) s += basis[b] * cp[r*NB + b];
            rad[r] = s * scale;
        }

        float q2[6] = {d0*d0, d1*d0, d2*d0, d1*d1, d2*d1, d2*d2};
        float q3[10] = {d0*q2[0], d1*q2[0], d0*q2[3], d1*q2[3], d2*q2[0],
                        d2*q2[1], d2*q2[3], d0*q2[5], d1*q2[5], d2*q2[5]};

#pragma unroll
        for (int r = 0; r < NR; r++) {
            float rv = rad[r];
            acc[r] += rv;
            acc[5 + r*3 + 0] += rv*d0;
            acc[5 + r*3 + 1] += rv*d1;
            acc[5 + r*3 + 2] += rv*d2;
#pragma unroll
            for (int q = 0; q < 6; q++)  acc[20 + r*6  + q] += rv*q2[q];
#pragma unroll
            for (int q = 0; q < 10; q++) acc[50 + r*10 + q] += rv*q3[q];
        }
    }

    // reduce over the 8 sub-lanes (groups of 8 are wave-aligned)
#pragma unroll
    for (int i = 0; i < MUS; i++) {
        float v = acc[i];
        v += __shfl_xor(v, 1, 64);
        v += __shfl_xor(v, 2, 64);
        v += __shfl_xor(v, 4, 64);
        if (sub == 0) red[al * MUS + i] = v;
    }
    __syncthreads();

    // coalesced flush
    for (int u = threadIdx.x; u < 32 * MUS; u += 256) {
        int ga = blockIdx.x * 32 + u / MUS;
        if (ga < NA) Mu[(size_t)ga * MUS + (u - (u / MUS) * MUS)] = red[u];
    }
}

// ---------------- pass 3: source-major contraction -----------------------
// For each contraction block b (width W, col offset off), source value
// C_b[l][a2] lands at out[a*360 + off + k] where f = l*NA + a2 = a*W + k.
// Lanes = consecutive atoms a2 -> LDS-staged Mu read exactly once from HBM,
// writes are runs of W consecutive floats.
__global__ __launch_bounds__(256) void contract_kernel(
    const float* __restrict__ Mu, float* __restrict__ out)
{
    __shared__ float lds[CHUNK * MPAD];
    int base = blockIdx.x * CHUNK;
    int nat  = min(CHUNK, NA - base);

    for (int t = threadIdx.x; t < nat * MUS; t += 256) {
        int al = t / MUS, off = t - al * MUS;
        lds[al * MPAD + off] = Mu[(size_t)base * MUS + t];
    }
    __syncthreads();

    int wave = threadIdx.x >> 6, lane = threadIdx.x & 63;
    int a2 = base + lane;
    bool valid = (lane < nat);
    int mb = lane * MPAD;   // LDS base offset for this lane's atom

#define ML(o) lds[mb + (o)]

    for (int cc = wave; cc < 360; cc += 4) {
        if (!valid) continue;
        float v; int dest;

        if (cc < 5) {
            v = ML(cc);
            dest = a2 * OC + cc;
        } else if (cc < 20) {
            int l = cc - 5;
            int r = T2I[l], s = T2J[l];
            float acc = 0.f;
#pragma unroll
            for (int i = 0; i < 3; i++) acc += ML(5 + r*3 + i) * ML(5 + s*3 + i);
            v = acc;
            int f = l * NA + a2; int a = f / 15; dest = a * OC + 5 + (f - a*15);
        } else if (cc < 35) {
            int l = cc - 20;
            int r = T2I[l], s = T2J[l];
            float acc = 0.f;
#pragma unroll
            for (int p = 0; p < 6; p++) acc += W2[p] * ML(20 + r*6 + p) * ML(20 + s*6 + p);
            v = acc;
            int f = l * NA + a2; int a = f / 15; dest = a * OC + 20 + (f - a*15);
        } else if (cc < 50) {
            int l = cc - 35;
            int r = T2I[l], s = T2J[l];
            float acc = 0.f;
#pragma unroll
            for (int p = 0; p < 10; p++) acc += W3[p] * ML(50 + r*10 + p) * ML(50 + s*10 + p);
            v = acc;
            int f = l * NA + a2; int a = f / 15; dest = a * OC + 35 + (f - a*15);
        } else if (cc < 85) {
            int l = cc - 50;
            int r = T3I[l], s = T3J[l], t = T3K[l];
            float R[6], S[6], T[6];
#pragma unroll
            for (int p = 0; p < 6; p++) { R[p]=ML(20+r*6+p); S[p]=ML(20+s*6+p); T[p]=ML(20+t*6+p); }
            float acc = 0.f;
#pragma unroll
            for (int i = 0; i < 3; i++)
#pragma unroll
            for (int j = 0; j < 3; j++)
#pragma unroll
            for (int k = 0; k < 3; k++)
                acc += R[P2[i*3+j]] * S[P2[i*3+k]] * T[P2[j*3+k]];
            v = acc;
            int f = l * NA + a2; int a = f / 35; dest = a * OC + 50 + (f - a*35);
        } else if (cc < 160) {
            int l = cc - 85;
            int p = l / 5, t = l - p*5;
            int r = T2I[p], s = T2J[p];
            float T[6];
#pragma unroll
            for (int q = 0; q < 6; q++) T[q] = ML(20 + t*6 + q);
            float acc = 0.f;
#pragma unroll
            for (int i = 0; i < 3; i++)
#pragma unroll
            for (int j = 0; j < 3; j++)
                acc += ML(5 + r*3 + i) * ML(5 + s*3 + j) * T[P2[i*3+j]];
            v = acc;
            int f = l * NA + a2; int a = f / 75; dest = a * OC + 85 + (f - a*75);
        } else if (cc < 235) {
            int l = cc - 160;
            int p = l / 5, t = l - p*5;
            int r = T2I[p], s = T2J[p];
            float R[10], S[10], T[6];
#pragma unroll
            for (int q = 0; q < 10; q++) { R[q]=ML(50+r*10+q); S[q]=ML(50+s*10+q); }
#pragma unroll
            for (int q = 0; q < 6;  q++) T[q] = ML(20 + t*6 + q);
            float acc = 0.f;
#pragma unroll
            for (int k = 0; k < 3; k++)
#pragma unroll
            for (int l2 = 0; l2 < 3; l2++) {
                float inner = 0.f;
#pragma unroll
                for (int i = 0; i < 3; i++)
#pragma unroll
                for (int j = 0; j < 3; j++)
                    inner += R[P3[(i*3+j)*3+k]] * S[P3[(i*3+j)*3+l2]];
                acc += inner * T[P2[k*3+l2]];
            }
            v = acc;
            int f = l * NA + a2; int a = f / 75; dest = a * OC + 160 + (f - a*75);
        } else {
            int l = cc - 235;
            int r = l / 25; int rem = l - r*25; int s = rem / 5; int t = rem - s*5;
            float R[10], S[6], T1[3];
#pragma unroll
            for (int q = 0; q < 10; q++) R[q] = ML(50 + r*10 + q);
#pragma unroll
            for (int q = 0; q < 6;  q++) S[q] = ML(20 + s*6 + q);
#pragma unroll
            for (int q = 0; q < 3;  q++) T1[q] = ML(5 + t*3 + q);
            float acc = 0.f;
#pragma unroll
            for (int i = 0; i < 3; i++)
#pragma unroll
            for (int j = 0; j < 3; j++)
#pragma unroll
            for (int k = 0; k < 3; k++)
                acc += R[P3[(i*3+j)*3+k]] * S[P2[i*3+j]] * T1[k];
            v = acc;
            int f = l * NA + a2; int a = f / 125; dest = a * OC + 235 + (f - a*125);
        }
        out[dest] = v;
    }
#undef ML
}

extern "C" void kernel_launch(void* const* d_in, const int* in_sizes, int n_in,
                              void* d_out, int out_size, void* d_ws, size_t ws_size,
                              hipStream_t stream) {
    const float* dr_vec = (const float*)d_in[0];
    const int*   Z      = (const int*)d_in[1];
    const int*   nbr    = (const int*)d_in[2];
    const float* coeffs = (const float*)d_in[3];
    float* out = (float*)d_out;

    // workspace layout: cursor[NA] | bins[NA*CAP] | Mu[NA*MUS]  (~21.3 MB)
    int*   cursor = (int*)d_ws;
    int*   bins   = cursor + NA;
    float* Mu     = (float*)(bins + (size_t)NA * CAP);

    hipMemsetAsync(cursor, 0, (size_t)NA * sizeof(int), stream);
    scatter_kernel<<<(NE + 255)/256, 256, 0, stream>>>(nbr, cursor, bins);
    accum_kernel<<<(NA*8 + 255)/256, 256, 0, stream>>>(dr_vec, Z, nbr, coeffs, cursor, bins, Mu);
    contract_kernel<<<(NA + CHUNK - 1)/CHUNK, 256, 0, stream>>>(Mu, out);
}

// Round 4
// 201.649 us; speedup vs baseline: 26.4935x; 1.4176x over previous
//
#include <hip/hip_runtime.h>
#include <math.h>

#define NR 5
#define NB 7
#define NS 119
#define NA 25000
#define NE 1000000
#define OC 360           // output columns per atom
#define MUS 100          // unique moment floats per atom
#define CAPR 104         // record bin capacity (lambda=40, P(overflow) ~1e-13)
#define CAPI 112         // id bin capacity (fallback path)
#define CHUNK 64         // atoms per contract block
#define MPAD 101         // LDS stride: 101 mod 32 = 5, gcd(5,32)=1 -> conflict-free

// tril index tables (wave-uniform index -> scalar loads)
static constexpr int T2I[15] = {0,1,1,2,2,2,3,3,3,3,4,4,4,4,4};
static constexpr int T2J[15] = {0,0,1,0,1,2,0,1,2,3,0,1,2,3,4};
static constexpr int T3I[35] = {0,1,1,1,2,2,2,2,2,2,3,3,3,3,3,3,3,3,3,3,4,4,4,4,4,4,4,4,4,4,4,4,4,4,4};
static constexpr int T3J[35] = {0,0,1,1,0,1,1,2,2,2,0,1,1,2,2,2,3,3,3,3,0,1,1,2,2,2,3,3,3,3,4,4,4,4,4};
static constexpr int T3K[35] = {0,0,0,1,0,0,1,0,1,2,0,0,1,0,1,2,0,1,2,3,0,0,1,0,1,2,0,1,2,3,0,1,2,3,4};

static constexpr int P2[9]  = {0,1,2, 1,3,4, 2,4,5};
static constexpr int P3[27] = {0,1,4, 1,2,5, 4,5,7,
                               1,2,5, 2,3,6, 5,6,8,
                               4,5,7, 5,6,8, 7,8,9};
static constexpr float W2[6]  = {1.f,2.f,2.f,1.f,2.f,1.f};
static constexpr float W3[10] = {1.f,3.f,3.f,1.f,3.f,6.f,3.f,3.f,3.f,1.f};

// ============================ FAST PATH ==================================
// pass 1: fused edge compute + record scatter.
// Coalesced reads (dr_vec, nbr sequential; Z/coeffs L2-resident gathers),
// per-edge record {rad[5]*cut*scale, d0,d1,d2} scattered as 32 B into bins.
__global__ __launch_bounds__(256) void edge_record_kernel(
    const float* __restrict__ dr_vec, const int* __restrict__ Z,
    const int* __restrict__ nbr, const float* __restrict__ coeffs,
    int* __restrict__ cursor, float* __restrict__ binrec)
{
    int e = blockIdx.x * 256 + threadIdx.x;
    if (e >= NE) return;
    float x = dr_vec[3*e+0], y = dr_vec[3*e+1], z = dr_vec[3*e+2];
    int ai = nbr[e];
    int aj = nbr[NE + e];
    int Zi = Z[ai], Zj = Z[aj];

    float dr  = sqrtf(x*x + y*y + z*z);
    float inv = 1.0f / (dr + 1e-5f);
    float d0 = x*inv, d1 = y*inv, d2 = z*inv;

    const float PI_F = 3.14159265358979323846f;
    const float betta = 49.0f / 36.0f;
    float rad_norm = powf(2.0f * betta / PI_F, 0.75f);
    float cut = (dr < 6.0f) ? 0.5f*(cosf(PI_F * dr * (1.0f/6.0f)) + 1.0f) : 0.0f;
    float scale = cut * 0.3779644730092272272f;   // 1/sqrt(7)

    float basis[NB];
#pragma unroll
    for (int b = 0; b < NB; b++) {
        float t = dr - (float)b;
        basis[b] = rad_norm * expf(-betta * t * t);
    }

    const float* cp = coeffs + ((size_t)(Zi*NS + Zj)) * (NR*NB);
    float rad[NR];
#pragma unroll
    for (int r = 0; r < NR; r++) {
        float s = 0.f;
#pragma unroll
        for (int b = 0; b < NB; b++) s += basis[b] * cp[r*NB + b];
        rad[r] = s * scale;
    }

    int pos = __hip_atomic_fetch_add(&cursor[aj], 1, __ATOMIC_RELAXED, __HIP_MEMORY_SCOPE_AGENT);
    if (pos < CAPR) {
        float4* rp = (float4*)(binrec + ((size_t)aj * CAPR + pos) * 8);
        rp[0] = make_float4(rad[0], rad[1], rad[2], rad[3]);
        rp[1] = make_float4(rad[4], d0, d1, d2);
    }
}

// pass 2: fused accumulate + contract. 4 lanes/atom x 64 atoms/block.
__global__ __launch_bounds__(256) void accum_contract_kernel(
    const int* __restrict__ cursor, const float* __restrict__ binrec,
    float* __restrict__ out)
{
    __shared__ float lds[CHUNK * MPAD];
    int base = blockIdx.x * CHUNK;
    int nat  = min(CHUNK, NA - base);

    int al  = threadIdx.x >> 2;          // local atom 0..63
    int sub = threadIdx.x & 3;
    int a   = base + al;
    int n   = (a < NA) ? min(cursor[a], CAPR) : 0;

    float acc[MUS];
#pragma unroll
    for (int i = 0; i < MUS; i++) acc[i] = 0.f;

    const float* mybin = binrec + (size_t)a * CAPR * 8;
    for (int p = sub; p < n; p += 4) {
        const float4* rp = (const float4*)(mybin + (size_t)p * 8);
        float4 r0 = rp[0], r1 = rp[1];
        float rad[NR] = {r0.x, r0.y, r0.z, r0.w, r1.x};
        float d0 = r1.y, d1 = r1.z, d2 = r1.w;

        float q2[6] = {d0*d0, d1*d0, d2*d0, d1*d1, d2*d1, d2*d2};
        float q3[10] = {d0*q2[0], d1*q2[0], d0*q2[3], d1*q2[3], d2*q2[0],
                        d2*q2[1], d2*q2[3], d0*q2[5], d1*q2[5], d2*q2[5]};

#pragma unroll
        for (int r = 0; r < NR; r++) {
            float rv = rad[r];
            acc[r] += rv;
            acc[5 + r*3 + 0] += rv*d0;
            acc[5 + r*3 + 1] += rv*d1;
            acc[5 + r*3 + 2] += rv*d2;
#pragma unroll
            for (int q = 0; q < 6; q++)  acc[20 + r*6  + q] += rv*q2[q];
#pragma unroll
            for (int q = 0; q < 10; q++) acc[50 + r*10 + q] += rv*q3[q];
        }
    }

    // reduce over 4 sub-lanes (within-wave groups), deposit into LDS tile
#pragma unroll
    for (int i = 0; i < MUS; i++) {
        float v = acc[i];
        v += __shfl_xor(v, 1, 64);
        v += __shfl_xor(v, 2, 64);
        if (sub == 0) lds[al * MPAD + i] = v;
    }
    __syncthreads();

    // ---- contract phase: lanes = atoms, waves split the 360 columns ----
    int wave = threadIdx.x >> 6, lane = threadIdx.x & 63;
    int a2 = base + lane;
    bool valid = (lane < nat);
    int mb = lane * MPAD;

#define ML(o) lds[mb + (o)]

    for (int cc = wave; cc < 360; cc += 4) {
        if (!valid) continue;
        float v; int dest;

        if (cc < 5) {
            v = ML(cc);
            dest = a2 * OC + cc;
        } else if (cc < 20) {
            int l = cc - 5;
            int r = T2I[l], s = T2J[l];
            float acc2 = 0.f;
#pragma unroll
            for (int i = 0; i < 3; i++) acc2 += ML(5 + r*3 + i) * ML(5 + s*3 + i);
            v = acc2;
            int f = l * NA + a2; int aa = f / 15; dest = aa * OC + 5 + (f - aa*15);
        } else if (cc < 35) {
            int l = cc - 20;
            int r = T2I[l], s = T2J[l];
            float acc2 = 0.f;
#pragma unroll
            for (int p = 0; p < 6; p++) acc2 += W2[p] * ML(20 + r*6 + p) * ML(20 + s*6 + p);
            v = acc2;
            int f = l * NA + a2; int aa = f / 15; dest = aa * OC + 20 + (f - aa*15);
        } else if (cc < 50) {
            int l = cc - 35;
            int r = T2I[l], s = T2J[l];
            float acc2 = 0.f;
#pragma unroll
            for (int p = 0; p < 10; p++) acc2 += W3[p] * ML(50 + r*10 + p) * ML(50 + s*10 + p);
            v = acc2;
            int f = l * NA + a2; int aa = f / 15; dest = aa * OC + 35 + (f - aa*15);
        } else if (cc < 85) {
            int l = cc - 50;
            int r = T3I[l], s = T3J[l], t = T3K[l];
            float R[6], S[6], T[6];
#pragma unroll
            for (int p = 0; p < 6; p++) { R[p]=ML(20+r*6+p); S[p]=ML(20+s*6+p); T[p]=ML(20+t*6+p); }
            float acc2 = 0.f;
#pragma unroll
            for (int i = 0; i < 3; i++)
#pragma unroll
            for (int j = 0; j < 3; j++)
#pragma unroll
            for (int k = 0; k < 3; k++)
                acc2 += R[P2[i*3+j]] * S[P2[i*3+k]] * T[P2[j*3+k]];
            v = acc2;
            int f = l * NA + a2; int aa = f / 35; dest = aa * OC + 50 + (f - aa*35);
        } else if (cc < 160) {
            int l = cc - 85;
            int p = l / 5, t = l - p*5;
            int r = T2I[p], s = T2J[p];
            float T[6];
#pragma unroll
            for (int q = 0; q < 6; q++) T[q] = ML(20 + t*6 + q);
            float acc2 = 0.f;
#pragma unroll
            for (int i = 0; i < 3; i++)
#pragma unroll
            for (int j = 0; j < 3; j++)
                acc2 += ML(5 + r*3 + i) * ML(5 + s*3 + j) * T[P2[i*3+j]];
            v = acc2;
            int f = l * NA + a2; int aa = f / 75; dest = aa * OC + 85 + (f - aa*75);
        } else if (cc < 235) {
            int l = cc - 160;
            int p = l / 5, t = l - p*5;
            int r = T2I[p], s = T2J[p];
            float R[10], S[10], T[6];
#pragma unroll
            for (int q = 0; q < 10; q++) { R[q]=ML(50+r*10+q); S[q]=ML(50+s*10+q); }
#pragma unroll
            for (int q = 0; q < 6;  q++) T[q] = ML(20 + t*6 + q);
            float acc2 = 0.f;
#pragma unroll
            for (int k = 0; k < 3; k++)
#pragma unroll
            for (int l2 = 0; l2 < 3; l2++) {
                float inner = 0.f;
#pragma unroll
                for (int i = 0; i < 3; i++)
#pragma unroll
                for (int j = 0; j < 3; j++)
                    inner += R[P3[(i*3+j)*3+k]] * S[P3[(i*3+j)*3+l2]];
                acc2 += inner * T[P2[k*3+l2]];
            }
            v = acc2;
            int f = l * NA + a2; int aa = f / 75; dest = aa * OC + 160 + (f - aa*75);
        } else {
            int l = cc - 235;
            int r = l / 25; int rem = l - r*25; int s = rem / 5; int t = rem - s*5;
            float R[10], S[6], T1[3];
#pragma unroll
            for (int q = 0; q < 10; q++) R[q] = ML(50 + r*10 + q);
#pragma unroll
            for (int q = 0; q < 6;  q++) S[q] = ML(20 + s*6 + q);
#pragma unroll
            for (int q = 0; q < 3;  q++) T1[q] = ML(5 + t*3 + q);
            float acc2 = 0.f;
#pragma unroll
            for (int i = 0; i < 3; i++)
#pragma unroll
            for (int j = 0; j < 3; j++)
#pragma unroll
            for (int k = 0; k < 3; k++)
                acc2 += R[P3[(i*3+j)*3+k]] * S[P2[i*3+j]] * T1[k];
            v = acc2;
            int f = l * NA + a2; int aa = f / 125; dest = aa * OC + 235 + (f - aa*125);
        }
        out[dest] = v;
    }
#undef ML
}

// ========================= FALLBACK PATH (round 3) =======================
__global__ __launch_bounds__(256) void scatter_kernel(
    const int* __restrict__ nbr, int* __restrict__ cursor, int* __restrict__ bins)
{
    int e = blockIdx.x * 256 + threadIdx.x;
    if (e >= NE) return;
    int aj = nbr[NE + e];
    int pos = __hip_atomic_fetch_add(&cursor[aj], 1, __ATOMIC_RELAXED, __HIP_MEMORY_SCOPE_AGENT);
    if (pos < CAPI) bins[(size_t)aj * CAPI + pos] = e;
}

__global__ __launch_bounds__(256) void accum_kernel(
    const float* __restrict__ dr_vec, const int* __restrict__ Z,
    const int* __restrict__ nbr, const float* __restrict__ coeffs,
    const int* __restrict__ cursor, const int* __restrict__ bins,
    float* __restrict__ Mu)
{
    __shared__ float red[32 * MUS];
    int t   = blockIdx.x * 256 + threadIdx.x;
    int a   = t >> 3;
    int sub = t & 7;
    int al  = threadIdx.x >> 3;
    int n   = (a < NA) ? min(cursor[a], CAPI) : 0;
    int Zj  = (a < NA) ? Z[a] : 0;

    float acc[MUS];
#pragma unroll
    for (int i = 0; i < MUS; i++) acc[i] = 0.f;

    const int* mybin = bins + (size_t)a * CAPI;
    const float PI_F = 3.14159265358979323846f;
    const float betta = 49.0f / 36.0f;
    float rad_norm = powf(2.0f * betta / PI_F, 0.75f);

    for (int p = sub; p < n; p += 8) {
        int e = mybin[p];
        float x = dr_vec[3*e+0], y = dr_vec[3*e+1], z = dr_vec[3*e+2];
        int Zi = Z[nbr[e]];

        float dr  = sqrtf(x*x + y*y + z*z);
        float inv = 1.0f / (dr + 1e-5f);
        float d0 = x*inv, d1 = y*inv, d2 = z*inv;

        float cut = (dr < 6.0f) ? 0.5f*(cosf(PI_F * dr * (1.0f/6.0f)) + 1.0f) : 0.0f;
        float scale = cut * 0.3779644730092272272f;

        float basis[NB];
#pragma unroll
        for (int b = 0; b < NB; b++) {
            float tt = dr - (float)b;
            basis[b] = rad_norm * expf(-betta * tt * tt);
        }

        const float* cp = coeffs + ((size_t)(Zi*NS + Zj)) * (NR*NB);
        float rad[NR];
#pragma unroll
        for (int r = 0; r < NR; r++) {
            float s = 0.f;
#pragma unroll
            for (int b = 0; b < NB; b++) s += basis[b] * cp[r*NB + b];
            rad[r] = s * scale;
        }

        float q2[6] = {d0*d0, d1*d0, d2*d0, d1*d1, d2*d1, d2*d2};
        float q3[10] = {d0*q2[0], d1*q2[0], d0*q2[3], d1*q2[3], d2*q2[0],
                        d2*q2[1], d2*q2[3], d0*q2[5], d1*q2[5], d2*q2[5]};

#pragma unroll
        for (int r = 0; r < NR; r++) {
            float rv = rad[r];
            acc[r] += rv;
            acc[5 + r*3 + 0] += rv*d0;
            acc[5 + r*3 + 1] += rv*d1;
            acc[5 + r*3 + 2] += rv*d2;
#pragma unroll
            for (int q = 0; q < 6; q++)  acc[20 + r*6  + q] += rv*q2[q];
#pragma unroll
            for (int q = 0; q < 10; q++) acc[50 + r*10 + q] += rv*q3[q];
        }
    }

#pragma unroll
    for (int i = 0; i < MUS; i++) {
        float v = acc[i];
        v += __shfl_xor(v, 1, 64);
        v += __shfl_xor(v, 2, 64);
        v += __shfl_xor(v, 4, 64);
        if (sub == 0) red[al * MUS + i] = v;
    }
    __syncthreads();

    for (int u = threadIdx.x; u < 32 * MUS; u += 256) {
        int ga = blockIdx.x * 32 + u / MUS;
        if (ga < NA) Mu[(size_t)ga * MUS + (u - (u / MUS) * MUS)] = red[u];
    }
}

__global__ __launch_bounds__(256) void contract_kernel(
    const float* __restrict__ Mu, float* __restrict__ out)
{
    __shared__ float lds[CHUNK * MPAD];
    int base = blockIdx.x * CHUNK;
    int nat  = min(CHUNK, NA - base);

    for (int t = threadIdx.x; t < nat * MUS; t += 256) {
        int al = t / MUS, off = t - al * MUS;
        lds[al * MPAD + off] = Mu[(size_t)base * MUS + t];
    }
    __syncthreads();

    int wave = threadIdx.x >> 6, lane = threadIdx.x & 63;
    int a2 = base + lane;
    bool valid = (lane < nat);
    int mb = lane * MPAD;

#define ML(o) lds[mb + (o)]

    for (int cc = wave; cc < 360; cc += 4) {
        if (!valid) continue;
        float v; int dest;

        if (cc < 5) {
            v = ML(cc);
            dest = a2 * OC + cc;
        } else if (cc < 20) {
            int l = cc - 5;
            int r = T2I[l], s = T2J[l];
            float acc = 0.f;
#pragma unroll
            for (int i = 0; i < 3; i++) acc += ML(5 + r*3 + i) * ML(5 + s*3 + i);
            v = acc;
            int f = l * NA + a2; int aa = f / 15; dest = aa * OC + 5 + (f - aa*15);
        } else if (cc < 35) {
            int l = cc - 20;
            int r = T2I[l], s = T2J[l];
            float acc = 0.f;
#pragma unroll
            for (int p = 0; p < 6; p++) acc += W2[p] * ML(20 + r*6 + p) * ML(20 + s*6 + p);
            v = acc;
            int f = l * NA + a2; int aa = f / 15; dest = aa * OC + 20 + (f - aa*15);
        } else if (cc < 50) {
            int l = cc - 35;
            int r = T2I[l], s = T2J[l];
            float acc = 0.f;
#pragma unroll
            for (int p = 0; p < 10; p++) acc += W3[p] * ML(50 + r*10 + p) * ML(50 + s*10 + p);
            v = acc;
            int f = l * NA + a2; int aa = f / 15; dest = aa * OC + 35 + (f - aa*15);
        } else if (cc < 85) {
            int l = cc - 50;
            int r = T3I[l], s = T3J[l], t = T3K[l];
            float R[6], S[6], T[6];
#pragma unroll
            for (int p = 0; p < 6; p++) { R[p]=ML(20+r*6+p); S[p]=ML(20+s*6+p); T[p]=ML(20+t*6+p); }
            float acc = 0.f;
#pragma unroll
            for (int i = 0; i < 3; i++)
#pragma unroll
            for (int j = 0; j < 3; j++)
#pragma unroll
            for (int k = 0; k < 3; k++)
                acc += R[P2[i*3+j]] * S[P2[i*3+k]] * T[P2[j*3+k]];
            v = acc;
            int f = l * NA + a2; int aa = f / 35; dest = aa * OC + 50 + (f - aa*35);
        } else if (cc < 160) {
            int l = cc - 85;
            int p = l / 5, t = l - p*5;
            int r = T2I[p], s = T2J[p];
            float T[6];
#pragma unroll
            for (int q = 0; q < 6; q++) T[q] = ML(20 + t*6 + q);
            float acc = 0.f;
#pragma unroll
            for (int i = 0; i < 3; i++)
#pragma unroll
            for (int j = 0; j < 3; j++)
                acc += ML(5 + r*3 + i) * ML(5 + s*3 + j) * T[P2[i*3+j]];
            v = acc;
            int f = l * NA + a2; int aa = f / 75; dest = aa * OC + 85 + (f - aa*75);
        } else if (cc < 235) {
            int l = cc - 160;
            int p = l / 5, t = l - p*5;
            int r = T2I[p], s = T2J[p];
            float R[10], S[10], T[6];
#pragma unroll
            for (int q = 0; q < 10; q++) { R[q]=ML(50+r*10+q); S[q]=ML(50+s*10+q); }
#pragma unroll
            for (int q = 0; q < 6;  q++) T[q] = ML(20 + t*6 + q);
            float acc = 0.f;
#pragma unroll
            for (int k = 0; k < 3; k++)
#pragma unroll
            for (int l2 = 0; l2 < 3; l2++) {
                float inner = 0.f;
#pragma unroll
                for (int i = 0; i < 3; i++)
#pragma unroll
                for (int j = 0; j < 3; j++)
                    inner += R[P3[(i*3+j)*3+k]] * S[P3[(i*3+j)*3+l2]];
                acc += inner * T[P2[k*3+l2]];
            }
            v = acc;
            int f = l * NA + a2; int aa = f / 75; dest = aa * OC + 160 + (f - aa*75);
        } else {
            int l = cc - 235;
            int r = l / 25; int rem = l - r*25; int s = rem / 5; int t = rem - s*5;
            float R[10], S[6], T1[3];
#pragma unroll
            for (int q = 0; q < 10; q++) R[q] = ML(50 + r*10 + q);
#pragma unroll
            for (int q = 0; q < 6;  q++) S[q] = ML(20 + s*6 + q);
#pragma unroll
            for (int q = 0; q < 3;  q++) T1[q] = ML(5 + t*3 + q);
            float acc = 0.f;
#pragma unroll
            for (int i = 0; i < 3; i++)
#pragma unroll
            for (int j = 0; j < 3; j++)
#pragma unroll
            for (int k = 0; k < 3; k++)
                acc += R[P3[(i*3+j)*3+k]] * S[P2[i*3+j]] * T1[k];
            v = acc;
            int f = l * NA + a2; int aa = f / 125; dest = aa * OC + 235 + (f - aa*125);
        }
        out[dest] = v;
    }
#undef ML
}

extern "C" void kernel_launch(void* const* d_in, const int* in_sizes, int n_in,
                              void* d_out, int out_size, void* d_ws, size_t ws_size,
                              hipStream_t stream) {
    const float* dr_vec = (const float*)d_in[0];
    const int*   Z      = (const int*)d_in[1];
    const int*   nbr    = (const int*)d_in[2];
    const float* coeffs = (const float*)d_in[3];
    float* out = (float*)d_out;

    // fast path needs: cursor[NA] ints + binrec[NA*CAPR*8] floats (~83.3 MB)
    size_t need_fast = (size_t)NA * sizeof(int) + (size_t)NA * CAPR * 8 * sizeof(float);

    if (ws_size >= need_fast) {
        int*   cursor = (int*)d_ws;
        float* binrec = (float*)(cursor + NA);
        hipMemsetAsync(cursor, 0, (size_t)NA * sizeof(int), stream);
        edge_record_kernel<<<(NE + 255)/256, 256, 0, stream>>>(dr_vec, Z, nbr, coeffs, cursor, binrec);
        accum_contract_kernel<<<(NA + CHUNK - 1)/CHUNK, 256, 0, stream>>>(cursor, binrec, out);
    } else {
        // round-3 fallback: cursor[NA] | bins[NA*CAPI] | Mu[NA*MUS] (~21.3 MB)
        int*   cursor = (int*)d_ws;
        int*   bins   = cursor + NA;
        float* Mu     = (float*)(bins + (size_t)NA * CAPI);
        hipMemsetAsync(cursor, 0, (size_t)NA * sizeof(int), stream);
        scatter_kernel<<<(NE + 255)/256, 256, 0, stream>>>(nbr, cursor, bins);
        accum_kernel<<<(NA*8 + 255)/256, 256, 0, stream>>>(dr_vec, Z, nbr, coeffs, cursor, bins, Mu);
        contract_kernel<<<(NA + CHUNK - 1)/CHUNK, 256, 0, stream>>>(Mu, out);
    }
}